// Round 2
// baseline (151.566 us; speedup 1.0000x reference)
//
#include <hip/hip_runtime.h>
#include <hip/hip_bf16.h>

// NNConv (edge-conditioned conv) x3 + MLP head.
// Trick: W_e = a0*A0 + a1*A1 + B  (affine in the 2 edge attrs), so
// aggr_n = (sum_e a0*x_src) @ A0 + (sum_e a1*x_src) @ A1 + (sum_e x_src) @ B.
// Build dst-CSR once per call (no atomics in the heavy phase), gather per node,
// one tiny dense matvec per node. Head fused into layer-3 kernel.

__global__ void hist_kernel(const int* __restrict__ dst, int* __restrict__ cnt, int E) {
    int e = blockIdx.x * blockDim.x + threadIdx.x;
    if (e < E) atomicAdd(&cnt[dst[e]], 1);
}

// Single-block exclusive scan over N counts -> off[0..N], cur = copy of off.
__global__ void scan_kernel(const int* __restrict__ cnt, int* __restrict__ off,
                            int* __restrict__ cur, int N) {
    __shared__ int part[256];
    int t = threadIdx.x;
    const int CH = (N + 255) / 256;
    int base = t * CH;
    int s = 0;
    for (int j = 0; j < CH; j++) {
        int idx = base + j;
        if (idx < N) s += cnt[idx];
    }
    part[t] = s;
    __syncthreads();
    // inclusive Hillis-Steele scan
    for (int d = 1; d < 256; d <<= 1) {
        int u = 0;
        if (t >= d) u = part[t - d];
        __syncthreads();
        part[t] += u;
        __syncthreads();
    }
    int running = part[t] - s;  // exclusive prefix for this chunk
    for (int j = 0; j < CH; j++) {
        int idx = base + j;
        if (idx < N) {
            off[idx] = running;
            cur[idx] = running;
            running += cnt[idx];
        }
    }
    if (t == 255) off[N] = part[255];
}

__global__ void scatter_kernel(const int* __restrict__ src, const int* __restrict__ dst,
                               const float* __restrict__ ea, int* __restrict__ cur,
                               int* __restrict__ s_src, float* __restrict__ s_a0,
                               float* __restrict__ s_a1, int E) {
    int e = blockIdx.x * blockDim.x + threadIdx.x;
    if (e < E) {
        int d = dst[e];
        int p = atomicAdd(&cur[d], 1);
        s_src[p] = src[e];
        s_a0[p] = ea[2 * e];
        s_a1[p] = ea[2 * e + 1];
    }
}

// Layer 1: in_c = 2, out_c = 32. 8 nodes per 256-thread block, 32 lanes per node
// (lane = output feature). Each lane redundantly accumulates the 6 gathered sums.
__global__ __launch_bounds__(256) void conv1_kernel(
    const float* __restrict__ x, const int* __restrict__ off,
    const int* __restrict__ s_src, const float* __restrict__ s_a0,
    const float* __restrict__ s_a1, const float* __restrict__ nnW,
    const float* __restrict__ nnb, const float* __restrict__ root,
    const float* __restrict__ bias, float* __restrict__ hout, int N) {
    int tid = threadIdx.x;
    int g = tid >> 5, lane = tid & 31;
    int n = blockIdx.x * 8 + g;
    if (n >= N) return;
    int beg = off[n], end = off[n + 1];
    float p0 = 0, p1 = 0, q0 = 0, q1 = 0, r0 = 0, r1 = 0;
    for (int p = beg; p < end; p++) {
        float a0 = s_a0[p], a1 = s_a1[p];
        int s = s_src[p];
        float x0 = x[2 * s], x1 = x[2 * s + 1];
        p0 = fmaf(a0, x0, p0);
        p1 = fmaf(a0, x1, p1);
        q0 = fmaf(a1, x0, q0);
        q1 = fmaf(a1, x1, q1);
        r0 += x0;
        r1 += x1;
    }
    // W[e,i,o] = a0*nnW[(i*32+o)*2] + a1*nnW[(i*32+o)*2+1] + nnb[i*32+o]
    float acc = bias[lane];
    acc = fmaf(p0, nnW[lane * 2], acc);
    acc = fmaf(p1, nnW[(32 + lane) * 2], acc);
    acc = fmaf(q0, nnW[lane * 2 + 1], acc);
    acc = fmaf(q1, nnW[(32 + lane) * 2 + 1], acc);
    acc = fmaf(r0, nnb[lane], acc);
    acc = fmaf(r1, nnb[32 + lane], acc);
    float x0n = x[2 * n], x1n = x[2 * n + 1];
    acc = fmaf(x0n, root[lane], acc);
    acc = fmaf(x1n, root[32 + lane], acc);
    hout[n * 32 + lane] = fmaxf(acc, 0.f);
}

// Layers 2/3: in_c = out_c = 32. 8 nodes/block, 32 lanes/node.
// Gather phase: lane = input feature, accumulate s0/s1/s2 + own h (s3).
// Matvec phase: lane = output feature, 128x32 matvec with weights in LDS.
// If `out` != null: fuse fc1(relu)+fc2 head and write [N,1] output instead of hout.
__global__ __launch_bounds__(256) void conv32_kernel(
    const float* __restrict__ hin, const int* __restrict__ off,
    const int* __restrict__ s_src, const float* __restrict__ s_a0,
    const float* __restrict__ s_a1, const float* __restrict__ nnW,
    const float* __restrict__ nnb, const float* __restrict__ root,
    const float* __restrict__ bias, float* __restrict__ hout,
    const float* __restrict__ fc1W, const float* __restrict__ fc1b,
    const float* __restrict__ fc2W, const float* __restrict__ fc2b,
    float* __restrict__ out, int N) {
    __shared__ float lA0[1024], lA1[1024], lB[1024], lR[1024];
    __shared__ float ls[8 * 128];
    __shared__ float lsH[256];
    int tid = threadIdx.x;
    for (int k = tid; k < 1024; k += 256) {
        lA0[k] = nnW[2 * k];
        lA1[k] = nnW[2 * k + 1];
        lB[k] = nnb[k];
        lR[k] = root[k];
    }
    __syncthreads();
    int g = tid >> 5, lane = tid & 31;
    int n = blockIdx.x * 8 + g;
    float s0 = 0, s1 = 0, s2 = 0, s3 = 0;
    if (n < N) {
        int beg = off[n], end = off[n + 1];
        for (int p = beg; p < end; p++) {
            float a0 = s_a0[p], a1 = s_a1[p];
            int s = s_src[p];
            float xv = hin[s * 32 + lane];
            s0 = fmaf(a0, xv, s0);
            s1 = fmaf(a1, xv, s1);
            s2 += xv;
        }
        s3 = hin[n * 32 + lane];
    }
    float* myls = &ls[g * 128];
    myls[lane] = s0;
    myls[32 + lane] = s1;
    myls[64 + lane] = s2;
    myls[96 + lane] = s3;
    __syncthreads();
    float acc = bias[lane];
#pragma unroll
    for (int i = 0; i < 32; i++) {
        acc = fmaf(myls[i], lA0[i * 32 + lane], acc);
        acc = fmaf(myls[32 + i], lA1[i * 32 + lane], acc);
        acc = fmaf(myls[64 + i], lB[i * 32 + lane], acc);
        acc = fmaf(myls[96 + i], lR[i * 32 + lane], acc);
    }
    acc = fmaxf(acc, 0.f);
    if (out == nullptr) {
        if (n < N) hout[n * 32 + lane] = acc;
    } else {
        lsH[g * 32 + lane] = acc;
        __syncthreads();
        float z = fc1b[lane];
#pragma unroll
        for (int o = 0; o < 32; o++) z = fmaf(lsH[g * 32 + o], fc1W[lane * 32 + o], z);
        z = fmaxf(z, 0.f);
        float v = z * fc2W[lane];
#pragma unroll
        for (int m = 1; m < 32; m <<= 1) v += __shfl_xor(v, m);
        if (lane == 0 && n < N) out[n] = v + fc2b[0];
    }
}

static inline size_t align256(size_t x) { return (x + 255) & ~(size_t)255; }

extern "C" void kernel_launch(void* const* d_in, const int* in_sizes, int n_in,
                              void* d_out, int out_size, void* d_ws, size_t ws_size,
                              hipStream_t stream) {
    const float* x = (const float*)d_in[0];
    const int* ei = (const int*)d_in[1];
    const float* ea = (const float*)d_in[2];
    const float* nn1W = (const float*)d_in[3];
    const float* nn1b = (const float*)d_in[4];
    const float* root1 = (const float*)d_in[5];
    const float* b1 = (const float*)d_in[6];
    const float* nn2W = (const float*)d_in[7];
    const float* nn2b = (const float*)d_in[8];
    const float* root2 = (const float*)d_in[9];
    const float* b2 = (const float*)d_in[10];
    const float* nn3W = (const float*)d_in[11];
    const float* nn3b = (const float*)d_in[12];
    const float* root3 = (const float*)d_in[13];
    const float* b3 = (const float*)d_in[14];
    const float* fc1W = (const float*)d_in[15];
    const float* fc1b = (const float*)d_in[16];
    const float* fc2W = (const float*)d_in[17];
    const float* fc2b = (const float*)d_in[18];

    const int N = in_sizes[0] / 2;   // 20000
    const int E = in_sizes[2] / 2;   // 150000
    const int* src = ei;             // edge_index[0]
    const int* dst = ei + E;         // edge_index[1]

    char* w = (char*)d_ws;
    int* cnt = (int*)w;      w += align256((size_t)N * 4);
    int* off = (int*)w;      w += align256((size_t)(N + 1) * 4);
    int* cur = (int*)w;      w += align256((size_t)N * 4);
    int* s_src = (int*)w;    w += align256((size_t)E * 4);
    float* s_a0 = (float*)w; w += align256((size_t)E * 4);
    float* s_a1 = (float*)w; w += align256((size_t)E * 4);
    float* h1 = (float*)w;   w += align256((size_t)N * 32 * 4);
    float* h2 = (float*)w;   w += align256((size_t)N * 32 * 4);

    float* out = (float*)d_out;

    hipMemsetAsync(cnt, 0, (size_t)N * 4, stream);

    int eb = (E + 255) / 256;
    hist_kernel<<<eb, 256, 0, stream>>>(dst, cnt, E);
    scan_kernel<<<1, 256, 0, stream>>>(cnt, off, cur, N);
    scatter_kernel<<<eb, 256, 0, stream>>>(src, dst, ea, cur, s_src, s_a0, s_a1, E);

    int nb = (N + 7) / 8;
    conv1_kernel<<<nb, 256, 0, stream>>>(x, off, s_src, s_a0, s_a1, nn1W, nn1b,
                                         root1, b1, h1, N);
    conv32_kernel<<<nb, 256, 0, stream>>>(h1, off, s_src, s_a0, s_a1, nn2W, nn2b,
                                          root2, b2, h2,
                                          nullptr, nullptr, nullptr, nullptr,
                                          nullptr, N);
    conv32_kernel<<<nb, 256, 0, stream>>>(h2, off, s_src, s_a0, s_a1, nn3W, nn3b,
                                          root3, b3, nullptr,
                                          fc1W, fc1b, fc2W, fc2b,
                                          out, N);
}

// Round 3
// 102.587 us; speedup vs baseline: 1.4774x; 1.4774x over previous
//
#include <hip/hip_runtime.h>
#include <hip/hip_bf16.h>

// NNConv (edge-conditioned conv) x3 + MLP head.
// W_e = a0*A0 + a1*A1 + B (affine in the 2 edge attrs), so
// aggr_n = (sum_e a0*x_src) @ A0 + (sum_e a1*x_src) @ A1 + (sum_e x_src) @ B.
// dst-CSR built per call: histogram -> 3-phase parallel scan -> scatter.
// Head (fc1+relu+fc2) fused into the layer-3 kernel.

__global__ void hist_kernel(const int* __restrict__ dst, int* __restrict__ cnt, int E) {
    int e = blockIdx.x * blockDim.x + threadIdx.x;
    if (e < E) atomicAdd(&cnt[dst[e]], 1);
}

// Phase A: per-block LDS scan; write per-element EXCLUSIVE prefix (within block)
// and per-block total.
__global__ __launch_bounds__(256) void scanA_kernel(const int* __restrict__ cnt,
                                                    int* __restrict__ esc,
                                                    int* __restrict__ bsum, int N) {
    __shared__ int sh[256];
    int t = threadIdx.x;
    int i = blockIdx.x * 256 + t;
    int v = (i < N) ? cnt[i] : 0;
    sh[t] = v;
    __syncthreads();
    for (int d = 1; d < 256; d <<= 1) {
        int u = (t >= d) ? sh[t - d] : 0;
        __syncthreads();
        sh[t] += u;
        __syncthreads();
    }
    if (i < N) esc[i] = sh[t] - v;
    if (t == 255) bsum[blockIdx.x] = sh[255];
}

// Phase B: single tiny block scans the NB block sums -> boff (exclusive), off[N]=total.
__global__ __launch_bounds__(128) void scanB_kernel(const int* __restrict__ bsum,
                                                    int* __restrict__ boff,
                                                    int* __restrict__ off, int NB, int N) {
    __shared__ int sh[128];
    int t = threadIdx.x;
    int v = (t < NB) ? bsum[t] : 0;
    sh[t] = v;
    __syncthreads();
    for (int d = 1; d < 128; d <<= 1) {
        int u = (t >= d) ? sh[t - d] : 0;
        __syncthreads();
        sh[t] += u;
        __syncthreads();
    }
    if (t < NB) boff[t] = sh[t] - v;
    if (t == 127) off[N] = sh[127];
}

// Phase C: off[i] = cur[i] = boff[block] + esc[i].
__global__ __launch_bounds__(256) void scanC_kernel(const int* __restrict__ esc,
                                                    const int* __restrict__ boff,
                                                    int* __restrict__ off,
                                                    int* __restrict__ cur, int N) {
    int i = blockIdx.x * 256 + threadIdx.x;
    if (i < N) {
        int o = boff[blockIdx.x] + esc[i];
        off[i] = o;
        cur[i] = o;
    }
}

__global__ void scatter_kernel(const int* __restrict__ src, const int* __restrict__ dst,
                               const float* __restrict__ ea, int* __restrict__ cur,
                               int* __restrict__ s_src, float* __restrict__ s_a0,
                               float* __restrict__ s_a1, int E) {
    int e = blockIdx.x * blockDim.x + threadIdx.x;
    if (e < E) {
        int d = dst[e];
        int p = atomicAdd(&cur[d], 1);
        s_src[p] = src[e];
        s_a0[p] = ea[2 * e];
        s_a1[p] = ea[2 * e + 1];
    }
}

// Layer 1: in_c = 2, out_c = 32. 8 nodes per 256-thread block, 32 lanes per node.
__global__ __launch_bounds__(256) void conv1_kernel(
    const float* __restrict__ x, const int* __restrict__ off,
    const int* __restrict__ s_src, const float* __restrict__ s_a0,
    const float* __restrict__ s_a1, const float* __restrict__ nnW,
    const float* __restrict__ nnb, const float* __restrict__ root,
    const float* __restrict__ bias, float* __restrict__ hout, int N) {
    int tid = threadIdx.x;
    int g = tid >> 5, lane = tid & 31;
    int n = blockIdx.x * 8 + g;
    if (n >= N) return;
    int beg = off[n], end = off[n + 1];
    float p0 = 0, p1 = 0, q0 = 0, q1 = 0, r0 = 0, r1 = 0;
    for (int p = beg; p < end; p++) {
        float a0 = s_a0[p], a1 = s_a1[p];
        int s = s_src[p];
        float x0 = x[2 * s], x1 = x[2 * s + 1];
        p0 = fmaf(a0, x0, p0);
        p1 = fmaf(a0, x1, p1);
        q0 = fmaf(a1, x0, q0);
        q1 = fmaf(a1, x1, q1);
        r0 += x0;
        r1 += x1;
    }
    float acc = bias[lane];
    acc = fmaf(p0, nnW[lane * 2], acc);
    acc = fmaf(p1, nnW[(32 + lane) * 2], acc);
    acc = fmaf(q0, nnW[lane * 2 + 1], acc);
    acc = fmaf(q1, nnW[(32 + lane) * 2 + 1], acc);
    acc = fmaf(r0, nnb[lane], acc);
    acc = fmaf(r1, nnb[32 + lane], acc);
    float x0n = x[2 * n], x1n = x[2 * n + 1];
    acc = fmaf(x0n, root[lane], acc);
    acc = fmaf(x1n, root[32 + lane], acc);
    hout[n * 32 + lane] = fmaxf(acc, 0.f);
}

// Layers 2/3: in_c = out_c = 32. 8 nodes/block, 32 lanes/node.
__global__ __launch_bounds__(256) void conv32_kernel(
    const float* __restrict__ hin, const int* __restrict__ off,
    const int* __restrict__ s_src, const float* __restrict__ s_a0,
    const float* __restrict__ s_a1, const float* __restrict__ nnW,
    const float* __restrict__ nnb, const float* __restrict__ root,
    const float* __restrict__ bias, float* __restrict__ hout,
    const float* __restrict__ fc1W, const float* __restrict__ fc1b,
    const float* __restrict__ fc2W, const float* __restrict__ fc2b,
    float* __restrict__ out, int N) {
    __shared__ float lA0[1024], lA1[1024], lB[1024], lR[1024];
    __shared__ float ls[8 * 128];
    __shared__ float lsH[256];
    int tid = threadIdx.x;
    for (int k = tid; k < 1024; k += 256) {
        lA0[k] = nnW[2 * k];
        lA1[k] = nnW[2 * k + 1];
        lB[k] = nnb[k];
        lR[k] = root[k];
    }
    __syncthreads();
    int g = tid >> 5, lane = tid & 31;
    int n = blockIdx.x * 8 + g;
    float s0 = 0, s1 = 0, s2 = 0, s3 = 0;
    if (n < N) {
        int beg = off[n], end = off[n + 1];
        for (int p = beg; p < end; p++) {
            float a0 = s_a0[p], a1 = s_a1[p];
            int s = s_src[p];
            float xv = hin[s * 32 + lane];
            s0 = fmaf(a0, xv, s0);
            s1 = fmaf(a1, xv, s1);
            s2 += xv;
        }
        s3 = hin[n * 32 + lane];
    }
    float* myls = &ls[g * 128];
    myls[lane] = s0;
    myls[32 + lane] = s1;
    myls[64 + lane] = s2;
    myls[96 + lane] = s3;
    __syncthreads();
    float acc = bias[lane];
#pragma unroll
    for (int i = 0; i < 32; i++) {
        acc = fmaf(myls[i], lA0[i * 32 + lane], acc);
        acc = fmaf(myls[32 + i], lA1[i * 32 + lane], acc);
        acc = fmaf(myls[64 + i], lB[i * 32 + lane], acc);
        acc = fmaf(myls[96 + i], lR[i * 32 + lane], acc);
    }
    acc = fmaxf(acc, 0.f);
    if (out == nullptr) {
        if (n < N) hout[n * 32 + lane] = acc;
    } else {
        lsH[g * 32 + lane] = acc;
        __syncthreads();
        float z = fc1b[lane];
#pragma unroll
        for (int o = 0; o < 32; o++) z = fmaf(lsH[g * 32 + o], fc1W[lane * 32 + o], z);
        z = fmaxf(z, 0.f);
        float v = z * fc2W[lane];
#pragma unroll
        for (int m = 1; m < 32; m <<= 1) v += __shfl_xor(v, m);
        if (lane == 0 && n < N) out[n] = v + fc2b[0];
    }
}

static inline size_t align256(size_t x) { return (x + 255) & ~(size_t)255; }

extern "C" void kernel_launch(void* const* d_in, const int* in_sizes, int n_in,
                              void* d_out, int out_size, void* d_ws, size_t ws_size,
                              hipStream_t stream) {
    const float* x = (const float*)d_in[0];
    const int* ei = (const int*)d_in[1];
    const float* ea = (const float*)d_in[2];
    const float* nn1W = (const float*)d_in[3];
    const float* nn1b = (const float*)d_in[4];
    const float* root1 = (const float*)d_in[5];
    const float* b1 = (const float*)d_in[6];
    const float* nn2W = (const float*)d_in[7];
    const float* nn2b = (const float*)d_in[8];
    const float* root2 = (const float*)d_in[9];
    const float* b2 = (const float*)d_in[10];
    const float* nn3W = (const float*)d_in[11];
    const float* nn3b = (const float*)d_in[12];
    const float* root3 = (const float*)d_in[13];
    const float* b3 = (const float*)d_in[14];
    const float* fc1W = (const float*)d_in[15];
    const float* fc1b = (const float*)d_in[16];
    const float* fc2W = (const float*)d_in[17];
    const float* fc2b = (const float*)d_in[18];

    const int N = in_sizes[0] / 2;   // 20000
    const int E = in_sizes[2] / 2;   // 150000
    const int* src = ei;             // edge_index[0]
    const int* dst = ei + E;         // edge_index[1]

    const int NB = (N + 255) / 256;  // 79 scan blocks

    char* w = (char*)d_ws;
    int* cnt = (int*)w;      w += align256((size_t)N * 4);
    int* off = (int*)w;      w += align256((size_t)(N + 1) * 4);
    int* cur = (int*)w;      w += align256((size_t)N * 4);
    int* esc = (int*)w;      w += align256((size_t)N * 4);
    int* bsum = (int*)w;     w += align256((size_t)NB * 4);
    int* boff = (int*)w;     w += align256((size_t)NB * 4);
    int* s_src = (int*)w;    w += align256((size_t)E * 4);
    float* s_a0 = (float*)w; w += align256((size_t)E * 4);
    float* s_a1 = (float*)w; w += align256((size_t)E * 4);
    float* h1 = (float*)w;   w += align256((size_t)N * 32 * 4);
    float* h2 = (float*)w;   w += align256((size_t)N * 32 * 4);

    float* out = (float*)d_out;

    hipMemsetAsync(cnt, 0, (size_t)N * 4, stream);

    int eb = (E + 255) / 256;
    hist_kernel<<<eb, 256, 0, stream>>>(dst, cnt, E);
    scanA_kernel<<<NB, 256, 0, stream>>>(cnt, esc, bsum, N);
    scanB_kernel<<<1, 128, 0, stream>>>(bsum, boff, off, NB, N);
    scanC_kernel<<<NB, 256, 0, stream>>>(esc, boff, off, cur, N);
    scatter_kernel<<<eb, 256, 0, stream>>>(src, dst, ea, cur, s_src, s_a0, s_a1, E);

    int nb = (N + 7) / 8;
    conv1_kernel<<<nb, 256, 0, stream>>>(x, off, s_src, s_a0, s_a1, nn1W, nn1b,
                                         root1, b1, h1, N);
    conv32_kernel<<<nb, 256, 0, stream>>>(h1, off, s_src, s_a0, s_a1, nn2W, nn2b,
                                          root2, b2, h2,
                                          nullptr, nullptr, nullptr, nullptr,
                                          nullptr, N);
    conv32_kernel<<<nb, 256, 0, stream>>>(h2, off, s_src, s_a0, s_a1, nn3W, nn3b,
                                          root3, b3, nullptr,
                                          fc1W, fc1b, fc2W, fc2b,
                                          out, N);
}